// Round 1
// baseline (74.776 us; speedup 1.0000x reference)
//
#include <hip/hip_runtime.h>
#include <math.h>

#define IMG 256
#define MAX_R 64

// ---------------------------------------------------------------------------
// Init: d_out is poisoned to 0xAA before every timed launch; we must set the
// whole image to 1.0f ourselves. 65536 floats = 16384 float4 stores.
// ---------------------------------------------------------------------------
__global__ void init_img_kernel(float4* __restrict__ img4) {
    int i = blockIdx.x * blockDim.x + threadIdx.x;
    if (i < (IMG * IMG) / 4) {
        img4[i] = make_float4(1.0f, 1.0f, 1.0f, 1.0f);
    }
}

// ---------------------------------------------------------------------------
// Render: one block per entity. All 256 threads redundantly compute the
// per-entity camera params (a few dozen f32 ops — cheaper than a broadcast),
// then stride over the disk bounding box doing atomicMin.
// depth >= 0 always, so float-min == unsigned-min on the bit patterns.
// ---------------------------------------------------------------------------
__global__ __launch_bounds__(256) void render_kernel(
    const float* __restrict__ agent_pos,
    const float* __restrict__ goal_pos,
    const float* __restrict__ other_agents,
    const float* __restrict__ obstacles,
    unsigned int* __restrict__ img,
    int n_ag, int n_ob)
{
    const int e = blockIdx.x;
    if (e >= n_ag + n_ob) return;

    // --- camera frame (replicates reference f32 op order) ---
    const float ax = agent_pos[0], ay = agent_pos[1];
    const float gx = goal_pos[0], gy = goal_pos[1];
    const float vx = gx - ax, vy = gy - ay;
    const float nrm = sqrtf(vx * vx + vy * vy) + 1e-8f;
    const float s = vx / nrm;   // view[0]
    const float c = vy / nrm;   // view[1]

    // --- entity params ---
    float ex, ey, radius, height;
    if (e < n_ag) {
        ex = other_agents[2 * e];
        ey = other_agents[2 * e + 1];
        radius = 0.05f;   // AGENT_RADIUS
        height = 0.2f;    // AGENT_HEIGHT
    } else {
        const int o = e - n_ag;
        ex = obstacles[3 * o];
        ey = obstacles[3 * o + 1];
        radius = obstacles[3 * o + 2];
        height = 0.5f;    // OBSTACLE_HEIGHT
    }

    const float rx = ex - ax, ry = ey - ay;
    // cam = rel @ rot.T ; rot = [[c, s], [-s, c]]
    const float cx = rx * c + ry * s;        // cam_x
    const float cy = ry * c - rx * s;        // cam_y
    const float dist = sqrtf(cx * cx + cy * cy);
    // arctan2 in double, cast to f32 ~= correctly-rounded f32 arctan2
    const float angle = (float)atan2((double)cx, (double)cy);

    const float half_fov = 0.78539816339744830962f; // f32(pi/4)
    const bool valid = (cy >= 0.0f) && (dist <= 3.0f) && (fabsf(angle) <= half_fov);
    if (!valid) return;   // vals==1.0 everywhere -> no-op on min-scatter

    const float pixel_x = angle / half_fov * 0.5f;
    const int px_int = (int)floorf((pixel_x + 0.5f) * 256.0f);

    int pr = (int)floorf(radius / (dist + 1e-8f) * 256.0f * 0.5f);
    pr = min(max(pr, 1), MAX_R);

    float depth = fminf(dist / 3.0f, 1.0f) * (1.0f - height * 0.3f);
    depth = fmaxf(depth, 0.0f);
    const unsigned int dbits = __float_as_uint(depth);

    const int side = 2 * pr + 1;
    const int total = side * side;
    const int rr = pr * pr;
    for (int i = threadIdx.x; i < total; i += blockDim.x) {
        const int row = i / side;
        const int col = i - row * side;
        const int dy = row - pr;
        const int dx = col - pr;
        if (dx * dx + dy * dy <= rr) {
            const int py = 128 + dy;        // IMG/2 + dy, always in [64,192]
            const int px = px_int + dx;
            if (px >= 0 && px < IMG && py >= 0 && py < IMG) {
                atomicMin(&img[py * IMG + px], dbits);
            }
        }
    }
}

extern "C" void kernel_launch(void* const* d_in, const int* in_sizes, int n_in,
                              void* d_out, int out_size, void* d_ws, size_t ws_size,
                              hipStream_t stream) {
    const float* agent_pos    = (const float*)d_in[0];
    const float* goal_pos     = (const float*)d_in[1];
    const float* other_agents = (const float*)d_in[2];
    const float* obstacles    = (const float*)d_in[3];

    const int n_ag = in_sizes[2] / 2;   // 2047
    const int n_ob = in_sizes[3] / 3;   // 2048

    float* img = (float*)d_out;

    init_img_kernel<<<(IMG * IMG / 4 + 255) / 256, 256, 0, stream>>>((float4*)img);
    render_kernel<<<n_ag + n_ob, 256, 0, stream>>>(
        agent_pos, goal_pos, other_agents, obstacles,
        (unsigned int*)img, n_ag, n_ob);
}